// Round 1
// baseline (526.421 us; speedup 1.0000x reference)
//
#include <hip/hip_runtime.h>

#define EMB_DIM 400
#define OUT_CH  6
#define ARITY   3
#define BATCH   8192
#define W_OUT   200     // (400-1)/2+1
#define FC_LEN  1200    // OUT_CH * W_OUT
#define BR      16      // batch rows per block
#define NK      25      // d-values per thread (400/16)

// Mt layout: float4 units, index (i*50 + wc)*400 + d  holds M_i[d][4wc..4wc+3]
// M_i[d][w] = sum_c (fc2_W[c][i] + fc2_b[c]) * fc_W[d][c*200 + w]
__global__ __launch_bounds__(256)
void build_M(const float* __restrict__ fc2_W, const float* __restrict__ fc2_b,
             const float* __restrict__ fc_W, float* __restrict__ Mt) {
    int idx = blockIdx.x * blockDim.x + threadIdx.x;
    if (idx >= ARITY * EMB_DIM * W_OUT) return;
    int j  = idx & 3;
    int d  = (idx >> 2) % EMB_DIM;
    int t  = (idx >> 2) / EMB_DIM;   // i*50 + wc
    int wc = t % 50;
    int i  = t / 50;
    int w  = wc * 4 + j;
    float s = 0.f;
#pragma unroll
    for (int c = 0; c < OUT_CH; ++c)
        s += (fc2_W[c*4 + i] + fc2_b[c]) * fc_W[d*FC_LEN + c*W_OUT + w];
    Mt[idx] = s;
}

__global__ __launch_bounds__(256)
void hype_main(const int* __restrict__ r_idx, const int* __restrict__ E_mat,
               const float* __restrict__ ms, const float* __restrict__ bs,
               const float* __restrict__ E_emb, const float* __restrict__ R_emb,
               const float* __restrict__ fc_b, const float4* __restrict__ Mt,
               float* __restrict__ out) {
    __shared__ float es[ARITY][BR][W_OUT];   // 38400 B
    const int tid = threadIdx.x;
    const int b0  = blockIdx.x * BR;

    // Stage gathered embedding rows (even columns only) into LDS.
    // 48 (i,r) pairs x 100 float4 loads each.
    for (int t = tid; t < ARITY * BR * 100; t += 256) {
        int j = t % 100;
        int p = t / 100;
        int r = p / ARITY;
        int i = p % ARITY;
        int ent = E_mat[(b0 + r) * ARITY + i];
        const float4 v = *reinterpret_cast<const float4*>(E_emb + (size_t)ent * EMB_DIM + 4 * j);
        es[i][r][2 * j]     = v.x;
        es[i][r][2 * j + 1] = v.z;
    }
    __syncthreads();

    const int dl = tid & 15;   // d-lane: d = dl + 16*k
    const int r  = tid >> 4;   // row within block
    const int b  = b0 + r;

    float prod[NK];
#pragma unroll
    for (int i = 0; i < ARITY; ++i) {
        float acc[NK];
#pragma unroll
        for (int k = 0; k < NK; ++k) acc[k] = 0.f;
        const float*  esr = &es[i][r][0];
        const float4* Mi  = Mt + (size_t)i * 50 * EMB_DIM;  // [wc][d] in float4 units
        for (int wc = 0; wc < 50; ++wc) {
            const float4 ev  = *reinterpret_cast<const float4*>(esr + 4 * wc);
            const float4* Mw = Mi + wc * EMB_DIM + dl;
#pragma unroll
            for (int k = 0; k < NK; ++k) {
                float4 mv = Mw[16 * k];
                acc[k] = fmaf(ev.x, mv.x, acc[k]);
                acc[k] = fmaf(ev.y, mv.y, acc[k]);
                acc[k] = fmaf(ev.z, mv.z, acc[k]);
                acc[k] = fmaf(ev.w, mv.w, acc[k]);
            }
        }
        const float mv_s = ms[b * ARITY + i];
        const float bv_s = bs[b * ARITY + i];
#pragma unroll
        for (int k = 0; k < NK; ++k) {
            float v = acc[k] + fc_b[dl + 16 * k];
            float e = fmaf(v, mv_s, bv_s);
            prod[k] = (i == 0) ? e : prod[k] * e;
        }
    }

    const int rr = r_idx[b];
    const float* Rrow = R_emb + (size_t)rr * EMB_DIM;
    float sum = 0.f;
#pragma unroll
    for (int k = 0; k < NK; ++k)
        sum += prod[k] * Rrow[dl + 16 * k];

    // reduce across the 16 d-lanes (same row)
#pragma unroll
    for (int m = 1; m < 16; m <<= 1)
        sum += __shfl_xor(sum, m, 64);
    if (dl == 0) out[b] = sum;
}

extern "C" void kernel_launch(void* const* d_in, const int* in_sizes, int n_in,
                              void* d_out, int out_size, void* d_ws, size_t ws_size,
                              hipStream_t stream) {
    const int*   r_idx = (const int*)d_in[0];
    const int*   E_mat = (const int*)d_in[1];
    const float* ms    = (const float*)d_in[2];
    const float* bs    = (const float*)d_in[3];
    const float* E_emb = (const float*)d_in[4];
    const float* R_emb = (const float*)d_in[5];
    const float* fc2_W = (const float*)d_in[6];
    const float* fc2_b = (const float*)d_in[7];
    const float* fc_W  = (const float*)d_in[8];
    const float* fc_b  = (const float*)d_in[9];
    float* out = (float*)d_out;
    float* Mt  = (float*)d_ws;   // needs 3*400*200*4 = 960000 B

    const int nM = ARITY * EMB_DIM * W_OUT;
    build_M<<<(nM + 255) / 256, 256, 0, stream>>>(fc2_W, fc2_b, fc_W, Mt);
    hype_main<<<BATCH / BR, 256, 0, stream>>>(r_idx, E_mat, ms, bs, E_emb, R_emb,
                                              fc_b, (const float4*)Mt, out);
}

// Round 2
// 36.130 us; speedup vs baseline: 14.5703x; 14.5703x over previous
//
#include <hip/hip_runtime.h>

typedef __attribute__((ext_vector_type(8))) short bf16x8;
typedef __attribute__((ext_vector_type(4))) float f32x4;

#define EMB_DIM 400
#define OUT_CH  6
#define ARITY   3
#define BATCH   8192
#define W_OUT   200
#define FC_LEN  1200
#define NT      25      // 16-wide col tiles (400/16)
#define NKS     7       // k-steps of 32 (K=200 padded to 224)
#define BM      32      // batch rows per block

static __device__ __forceinline__ ushort f2bf(float f) {
    union { float f; uint u; } v; v.f = f;
    uint u = v.u;
    return (ushort)((u + 0x7FFF + ((u >> 16) & 1)) >> 16);   // RNE
}

// Mb layout: for (i, t, kk): 64 lanes x 8 bf16; lane l, elem j holds
//   B[w = kk*32 + (l>>4)*8 + j][d = t*16 + (l&15)]  (w>=200 -> 0)
// where B = M_i[w][d] = sum_c (fc2_W[c][i]+fc2_b[c]) * fc_W[d][c*200+w]
__global__ __launch_bounds__(256)
void pack_M(const float* __restrict__ fc2_W, const float* __restrict__ fc2_b,
            const float* __restrict__ fc_W, ushort* __restrict__ Mb) {
    __shared__ float Bt[224][16];
    const int bid = blockIdx.x;            // i*25 + t
    const int i = bid / NT, t = bid % NT;
    float kc[OUT_CH];
#pragma unroll
    for (int c = 0; c < OUT_CH; ++c) kc[c] = fc2_W[c * 4 + i] + fc2_b[c];
    const int tid = threadIdx.x;
    const int dd = tid >> 4, wl = tid & 15;
    const int d = t * 16 + dd;
#pragma unroll
    for (int s = 0; s < 14; ++s) {
        int w = wl + 16 * s;
        float v = 0.f;
        if (w < W_OUT) {
#pragma unroll
            for (int c = 0; c < OUT_CH; ++c)
                v = fmaf(kc[c], fc_W[d * FC_LEN + c * W_OUT + w], v);
        }
        Bt[w][dd] = v;
    }
    __syncthreads();
    const int l = tid & 63;
    for (int kk = tid >> 6; kk < NKS; kk += 4) {
        ushort vals[8];
#pragma unroll
        for (int j = 0; j < 8; ++j)
            vals[j] = f2bf(Bt[kk * 32 + (l >> 4) * 8 + j][l & 15]);
        *reinterpret_cast<uint4*>(Mb + ((size_t)(bid * NKS + kk) * 64 + l) * 8) =
            *reinterpret_cast<const uint4*>(vals);
    }
}

__global__ __launch_bounds__(512)
void hype_mfma(const int* __restrict__ r_idx, const int* __restrict__ E_mat,
               const float* __restrict__ ms, const float* __restrict__ bs,
               const float* __restrict__ E_emb, const float* __restrict__ R_emb,
               const float* __restrict__ fc_b, const ushort* __restrict__ Mb,
               float* __restrict__ out) {
    // es: A-fragments. chunk (i, rg, kk) = 64 lanes * 16B, lane-linear.
    __shared__ ushort es[ARITY * 2 * NKS * 64 * 8];   // 43008 B
    __shared__ float sm_ms[BM * 3], sm_bs[BM * 3], sm_fcb[EMB_DIM];
    __shared__ int   sm_rb[BM];
    __shared__ float osum[4][BM];

    const int tid = threadIdx.x;
    const int b0 = blockIdx.x * BM;

    if (tid < BM * 3) { sm_ms[tid] = ms[b0 * 3 + tid]; sm_bs[tid] = bs[b0 * 3 + tid]; }
    if (tid >= 96 && tid < 96 + BM) sm_rb[tid - 96] = r_idx[b0 + tid - 96] * EMB_DIM;
    if (tid >= 112 && tid < 112 + EMB_DIM) sm_fcb[tid - 112] = fc_b[tid - 112];

    uint* esu = reinterpret_cast<uint*>(es);
    // zero the K-pad: kk=6, lane>=16 regions: 6 pairs * 192 uints
    for (int z = tid; z < ARITY * 2 * 192; z += 512) {
        int pair = z / 192, off = z % 192;
        esu[(pair * NKS + 6) * 256 + 64 + off] = 0;
    }
    // gather embeddings (even cols), convert to bf16, write in A-frag order
    for (int tq = tid; tq < ARITY * BM * 100; tq += 512) {
        int q = tq % 100;
        int p = tq / 100;
        int i = p / BM, r = p % BM;
        int ent = E_mat[(b0 + r) * ARITY + i];
        const float4 v = *reinterpret_cast<const float4*>(E_emb + (size_t)ent * EMB_DIM + 4 * q);
        int w = 2 * q;                    // covers w, w+1 (always same 8-block)
        int kk = w >> 5;
        int lsub = (w >> 3) & 3;
        int j = w & 7;                    // even
        int rg = r >> 4, rl = r & 15;
        int l = lsub * 16 + rl;
        uint pk = (uint)f2bf(v.x) | ((uint)f2bf(v.z) << 16);
        esu[(((i * 2 + rg) * NKS + kk) * 64 + l) * 4 + (j >> 1)] = pk;
    }
    __syncthreads();

    const int wid = tid >> 6;
    const int lane = tid & 63;
    const int rg = wid & 1, cg = wid >> 1;     // rg: row-group, cg: col-group
    const int cl = lane & 15;                   // col within tile
    const int rql = lane >> 4;                  // row quad

    // preload all A fragments for this wave's 16 rows (3 i * 7 kk)
    bf16x8 afrag[ARITY][NKS];
#pragma unroll
    for (int i = 0; i < ARITY; ++i)
#pragma unroll
        for (int kk = 0; kk < NKS; ++kk)
            afrag[i][kk] = *reinterpret_cast<const bf16x8*>(
                es + (((i * 2 + rg) * NKS + kk) * 64 + lane) * 8);

    float msv[ARITY][4], bsv[ARITY][4];
    int rbv[4];
#pragma unroll
    for (int r_ = 0; r_ < 4; ++r_) {
        int row = rg * 16 + rql * 4 + r_;
#pragma unroll
        for (int i = 0; i < ARITY; ++i) {
            msv[i][r_] = sm_ms[row * 3 + i];
            bsv[i][r_] = sm_bs[row * 3 + i];
        }
        rbv[r_] = sm_rb[row];
    }

    float rowsum[4] = {0.f, 0.f, 0.f, 0.f};
    for (int t = cg; t < NT; t += 4) {
        f32x4 acc[ARITY];
#pragma unroll
        for (int i = 0; i < ARITY; ++i) {
            f32x4 a = {0.f, 0.f, 0.f, 0.f};
            const ushort* bp = Mb + ((size_t)(i * NT + t) * NKS * 64 + lane) * 8;
#pragma unroll
            for (int kk = 0; kk < NKS; ++kk) {
                bf16x8 bfr = *reinterpret_cast<const bf16x8*>(bp + kk * 512);
                a = __builtin_amdgcn_mfma_f32_16x16x32_bf16(afrag[i][kk], bfr, a, 0, 0, 0);
            }
            acc[i] = a;
        }
        const int d = t * 16 + cl;
        const float fcb = sm_fcb[d];
#pragma unroll
        for (int r_ = 0; r_ < 4; ++r_) {
            float Rr = R_emb[rbv[r_] + d];
            float e0 = fmaf(acc[0][r_] + fcb, msv[0][r_], bsv[0][r_]);
            float e1 = fmaf(acc[1][r_] + fcb, msv[1][r_], bsv[1][r_]);
            float e2 = fmaf(acc[2][r_] + fcb, msv[2][r_], bsv[2][r_]);
            rowsum[r_] = fmaf(e0 * e1 * e2, Rr, rowsum[r_]);
        }
    }

#pragma unroll
    for (int m = 1; m < 16; m <<= 1)
#pragma unroll
        for (int r_ = 0; r_ < 4; ++r_)
            rowsum[r_] += __shfl_xor(rowsum[r_], m, 64);
    if (cl == 0) {
#pragma unroll
        for (int r_ = 0; r_ < 4; ++r_)
            osum[cg][rg * 16 + rql * 4 + r_] = rowsum[r_];
    }
    __syncthreads();
    if (tid < BM)
        out[b0 + tid] = osum[0][tid] + osum[1][tid] + osum[2][tid] + osum[3][tid];
}

extern "C" void kernel_launch(void* const* d_in, const int* in_sizes, int n_in,
                              void* d_out, int out_size, void* d_ws, size_t ws_size,
                              hipStream_t stream) {
    const int*   r_idx = (const int*)d_in[0];
    const int*   E_mat = (const int*)d_in[1];
    const float* ms    = (const float*)d_in[2];
    const float* bs    = (const float*)d_in[3];
    const float* E_emb = (const float*)d_in[4];
    const float* R_emb = (const float*)d_in[5];
    const float* fc2_W = (const float*)d_in[6];
    const float* fc2_b = (const float*)d_in[7];
    const float* fc_W  = (const float*)d_in[8];
    const float* fc_b  = (const float*)d_in[9];
    float*  out = (float*)d_out;
    ushort* Mb  = (ushort*)d_ws;     // 3*25*7*64*8*2 = 537600 B

    pack_M<<<ARITY * NT, 256, 0, stream>>>(fc2_W, fc2_b, fc_W, Mb);
    hype_mfma<<<BATCH / BM, 512, 0, stream>>>(r_idx, E_mat, ms, bs, E_emb, R_emb,
                                              fc_b, Mb, out);
}